// Round 10
// baseline (156.752 us; speedup 1.0000x reference)
//
#include <hip/hip_runtime.h>
#include <hip/hip_bf16.h>
#include <stdint.h>
#include <stddef.h>

// ---------------------------------------------------------------------------
// ResAttnBlock: GroupNorm -> QKV -> full spatial attention -> proj -> residual
// B=32, C=256, S=32 (P=1024 positions), 32 groups of 8 channels.
// All GEMM-shaped work on v_mfma_f32_16x16x32_bf16; fp32 accumulate.
// ---------------------------------------------------------------------------

typedef float  f32x4  __attribute__((ext_vector_type(4)));
typedef __bf16 bf16x8 __attribute__((ext_vector_type(8)));
typedef __bf16 bf16x4 __attribute__((ext_vector_type(4)));

#define DEVI static __device__ __forceinline__

DEVI f32x4 mfma16(bf16x8 a, bf16x8 b, f32x4 c) {
  return __builtin_amdgcn_mfma_f32_16x16x32_bf16(a, b, c, 0, 0, 0);
}

DEVI f32x4 zero4() { f32x4 z = {0.f, 0.f, 0.f, 0.f}; return z; }

typedef const __attribute__((address_space(1))) void* gas_cvp;
typedef __attribute__((address_space(3))) void*       las_vp;

DEVI void gl_lds16(const __bf16* g, __bf16* l) {
  // async global->LDS, 16B per lane; LDS dest = uniform base + lane*16
  __builtin_amdgcn_global_load_lds((gas_cvp)g, (las_vp)l, 16, 0, 0);
}

#define WAIT_VM(N) asm volatile("s_waitcnt vmcnt(" #N ")" ::: "memory")
DEVI void bar() {
  asm volatile("" ::: "memory");
  __builtin_amdgcn_s_barrier();
  asm volatile("" ::: "memory");
}

// ---------------------------------------------------------------------------
// Kernel 0: convert weights to bf16 (w_attn 768x256, w_proj 256x256)
// ---------------------------------------------------------------------------
__global__ __launch_bounds__(256) void cvt_weights(
    const float* __restrict__ wa, const float* __restrict__ wp,
    __bf16* __restrict__ wab, __bf16* __restrict__ wpb) {
  const int i = blockIdx.x * 256 + threadIdx.x;
  if (i < 196608) {
    wab[i] = (__bf16)wa[i];
  } else {
    const int j = i - 196608;
    if (j < 65536) wpb[j] = (__bf16)wp[j];
  }
}

// ---------------------------------------------------------------------------
// Kernel 1: fused GroupNorm (stats + apply + transpose), single x pass.
// ---------------------------------------------------------------------------
__global__ __launch_bounds__(256) void gn_fused(
    const float* __restrict__ x, const float* __restrict__ gamma,
    const float* __restrict__ beta, __bf16* __restrict__ h) {
  __shared__ __align__(16) float xs[8192];
  __shared__ float redS[4], redSS[4];
  const int bg = blockIdx.x;           // b*32+g
  const int b = bg >> 5, g = bg & 31;
  const int tid = threadIdx.x;
  const float* base = x + (size_t)bg * 8192;
  float s = 0.f, ss = 0.f;
#pragma unroll
  for (int it = 0; it < 8; ++it) {
    const int i = it * 256 + tid;      // f32x4 chunk index
    f32x4 v = *(const f32x4*)(base + i * 4);
    *(f32x4*)(xs + i * 4) = v;
    s  += v[0] + v[1] + v[2] + v[3];
    ss += v[0]*v[0] + v[1]*v[1] + v[2]*v[2] + v[3]*v[3];
  }
#pragma unroll
  for (int m = 1; m < 64; m <<= 1) {
    s  += __shfl_xor(s,  m, 64);
    ss += __shfl_xor(ss, m, 64);
  }
  const int lane = tid & 63, wave = tid >> 6;
  if (lane == 0) { redS[wave] = s; redSS[wave] = ss; }
  __syncthreads();
  const float S  = redS[0] + redS[1] + redS[2] + redS[3];
  const float SS = redSS[0] + redSS[1] + redSS[2] + redSS[3];
  const float mu = S * (1.f / 8192.f);
  const float rstd = rsqrtf(SS * (1.f / 8192.f) - mu * mu + 1e-5f);
  float ga[8], be[8];
#pragma unroll
  for (int j = 0; j < 8; ++j) {
    const int c = g * 8 + j;
    ga[j] = gamma[c] * rstd;
    be[j] = beta[c] - mu * ga[j];
  }
  __bf16* hb = h + ((size_t)b << 18) + g * 8;   // h[b][p][c]
#pragma unroll
  for (int it = 0; it < 4; ++it) {
    const int p = it * 256 + tid;
    bf16x8 o8;
#pragma unroll
    for (int j = 0; j < 8; ++j)
      o8[j] = (__bf16)(xs[j * 1024 + p] * ga[j] + be[j]);
    *(bf16x8*)(hb + ((size_t)p << 8)) = o8;
  }
}

// ---------------------------------------------------------------------------
// Shared GEMM core: C(128x128) = A(128xK=256) * Bt(128 rows x 256)^T
// 4 waves (2x2), each 64x64 = 4x4 frags. BK=64, 4 k-outer steps.
// ---------------------------------------------------------------------------
DEVI void gemm_core_k256(const __bf16* __restrict__ A0, const __bf16* __restrict__ B0,
                         __bf16* lA, __bf16* lB, int lane, int wave, f32x4 acc[4][4]) {
  const int wm = (wave >> 1) * 64;
  const int wn = (wave & 1) * 64;
  const int r15 = lane & 15, lg = lane >> 4;
#pragma unroll
  for (int i = 0; i < 4; ++i)
#pragma unroll
    for (int j = 0; j < 4; ++j) acc[i][j] = zero4();

  for (int ko = 0; ko < 4; ++ko) {
#pragma unroll
    for (int it = 0; it < 4; ++it) {
      const int q = wave * 256 + it * 64 + lane;
      const int row = q >> 3, c8 = q & 7;
      const int srcoff = row * 256 + ko * 64 + ((c8 ^ (row & 7)) << 3);
      gl_lds16(A0 + srcoff, lA + (size_t)(wave * 256 + it * 64) * 8);
      gl_lds16(B0 + srcoff, lB + (size_t)(wave * 256 + it * 64) * 8);
    }
    __syncthreads();
#pragma unroll
    for (int kk = 0; kk < 2; ++kk) {
      bf16x8 af[4], bfr[4];
#pragma unroll
      for (int i = 0; i < 4; ++i) {
        const int row = wm + i * 16 + r15;
        af[i] = *(const bf16x8*)((const char*)lA + row * 128 +
                                 (((kk * 4 + lg) ^ (row & 7)) << 4));
      }
#pragma unroll
      for (int j = 0; j < 4; ++j) {
        const int row = wn + j * 16 + r15;
        bfr[j] = *(const bf16x8*)((const char*)lB + row * 128 +
                                  (((kk * 4 + lg) ^ (row & 7)) << 4));
      }
#pragma unroll
      for (int i = 0; i < 4; ++i)
#pragma unroll
        for (int j = 0; j < 4; ++j) acc[i][j] = mfma16(af[i], bfr[j], acc[i][j]);
    }
    __syncthreads();
  }
}

// ---------------------------------------------------------------------------
// Kernel 3: QKV GEMM. h(32768x256) @ w_attn(768x256)^T + bias.
// ---------------------------------------------------------------------------
__global__ __launch_bounds__(256) void qkv_gemm(
    const __bf16* __restrict__ h, const __bf16* __restrict__ wab,
    const float* __restrict__ b_attn,
    __bf16* __restrict__ q, __bf16* __restrict__ k, __bf16* __restrict__ vt) {
  __shared__ __align__(16) __bf16 lA[128 * 64], lB[128 * 64];
  const int nt = blockIdx.x, mt = blockIdx.y;
  const int tid = threadIdx.x, lane = tid & 63, wave = tid >> 6;
  f32x4 acc[4][4];
  gemm_core_k256(h + (size_t)mt * 128 * 256, wab + (size_t)nt * 128 * 256,
                 lA, lB, lane, wave, acc);

  const int wm = (wave >> 1) * 64, wn = (wave & 1) * 64;
  const int r15 = lane & 15, lg = lane >> 4;
  const int sec = nt >> 1;  // 0=q, 1=k, 2=v
  const float QS = 0.0625f * 1.44269504088896340736f;  // (1/sqrt(256))*log2(e)
#pragma unroll
  for (int j = 0; j < 4; ++j) {
    const int ng = nt * 128 + wn + j * 16 + r15;
    const float bias = b_attn[ng];
    const int c = ng & 255;
#pragma unroll
    for (int i = 0; i < 4; ++i) {
      const int mbase = mt * 128 + wm + i * 16 + lg * 4;
      if (sec == 0) {
#pragma unroll
        for (int r = 0; r < 4; ++r)
          q[(size_t)(mbase + r) * 256 + c] = (__bf16)((acc[i][j][r] + bias) * QS);
      } else if (sec == 1) {
#pragma unroll
        for (int r = 0; r < 4; ++r)
          k[(size_t)(mbase + r) * 256 + c] = (__bf16)(acc[i][j][r] + bias);
      } else {
        const int b = mbase >> 10, p = mbase & 1023;
        bf16x4 pk;
#pragma unroll
        for (int r = 0; r < 4; ++r) pk[r] = (__bf16)(acc[i][j][r] + bias);
        *(bf16x4*)(vt + (((size_t)(b * 256 + c)) << 10) + p) = pk;
      }
    }
  }
}

// ---------------------------------------------------------------------------
// Kernel 4: flash attention, KV-split inside a 256-thread block.
// EMPIRICAL RULE (R2/R6 vs R8/R9): 512-thread blocks are allocator-capped
// at 128 VGPR (spill); 256-thread blocks can allocate ~256. So: 4 waves =
// 2 kv-groups x 2 waves, each wave m=32 q-rows (~235 VGPR, no spill at
// (256,1)). Block = 64 q-rows x full kv; grid 512 = 2 blocks/CU (72KB LDS)
// -> 2 waves/SIMD from independent blocks (cross-block phase overlap)
// AND m=32's halved LDS streaming. Counted-vmcnt single-buffer schedule.
// In-block flash-merge of the kv-halves between wave pairs at the end.
// ---------------------------------------------------------------------------
__global__ __launch_bounds__(256, 1) void attn(
    const __bf16* __restrict__ q, const __bf16* __restrict__ k,
    const __bf16* __restrict__ vt, __bf16* __restrict__ o) {
  extern __shared__ __align__(16) char smem[];   // 73728 B
  // KB: grp0 @0, grp1 @16384   ([32 kv][256 k] swz, 16KB each)
  // VB: grp0 @32768, grp1 @49152 ([256 d][32 kv] swz, 16KB each)
  // P : @65536 + wave*2048      ([32 q][32 kv] swz, 2KB/wave)

  const int bid = blockIdx.x;
  const int xcd = bid & 7, sub = bid >> 3;       // sub 0..63
  const int b = xcd * 4 + (sub & 3);             // same-b blocks share an XCD
  const int qt = sub >> 2;                       // 0..15
  const int tid = threadIdx.x, lane = tid & 63, wave = tid >> 6;
  const int w2 = wave & 1, grp = wave >> 1;      // grp0: kv 0..511, grp1: 512..1023
  const int gtid = tid & 127;                    // tid within kv-group (128 thr)
  const int r15 = lane & 15, lg = lane >> 4, rs7 = r15 & 7;
  const int m0 = qt * 64 + w2 * 32;
  char* KB = smem + grp * 16384;
  char* VB = smem + 32768 + grp * 16384;
  char* P  = smem + 65536 + wave * 2048;

  const __bf16* kb = k  + ((size_t)b << 18);
  const __bf16* vb = vt + ((size_t)b << 18);
  const int kvbase = grp * 512;
  const int pswz = (r15 ^ (r15 >> 2)) & 3;       // P-row swizzle (64B rows)

  // Q fragments: 2 q-halves x 8 k-chunks (64 VGPR)
  const __bf16* qbp = q + (((size_t)(b * 1024 + m0)) << 8);
  bf16x8 qf[2][8];
#pragma unroll
  for (int qh = 0; qh < 2; ++qh)
#pragma unroll
    for (int kc = 0; kc < 8; ++kc)
      qf[qh][kc] = *(const bf16x8*)(qbp + (size_t)(qh * 16 + r15) * 256 + kc * 32 + lg * 8);

  f32x4 po[16][2];   // po[df][qh][r] = O[q=qh*16+r15][d=df*16+lg*4+r] (partial)
#pragma unroll
  for (int d = 0; d < 16; ++d)
#pragma unroll
    for (int qh = 0; qh < 2; ++qh) po[d][qh] = zero4();
  float mrun[2] = {-1e30f, -1e30f}, lrun[2] = {0.f, 0.f};

  // staging per kv-group (128 threads): 1024 16B-chunks/tile, 8/thread
  auto stageK = [&](int n0) {
    __bf16* dst = (__bf16*)KB;
#pragma unroll
    for (int it = 0; it < 8; ++it) {
      const int qch = it * 128 + gtid;           // [32 rows][32 chunks]
      const int row = qch >> 5, c32 = qch & 31;
      gl_lds16(kb + (size_t)(n0 + row) * 256 + ((c32 ^ (row & 7)) << 3),
               dst + (size_t)(it * 128 + w2 * 64) * 8);
    }
  };
  auto stageV = [&](int n0) {
    __bf16* dst = (__bf16*)VB;
#pragma unroll
    for (int it = 0; it < 8; ++it) {
      const int qch = it * 128 + gtid;           // [256 rows][4 chunks]
      const int row = qch >> 2, c4 = qch & 3;
      gl_lds16(vb + ((size_t)row << 10) + n0 + ((c4 ^ ((row ^ (row >> 2)) & 3)) << 3),
               dst + (size_t)(it * 128 + w2 * 64) * 8);
    }
  };

  stageK(kvbase);
  stageV(kvbase);

  for (int t = 0; t < 16; ++t) {
    const int n0n = kvbase + (t + 1) * 32;
    WAIT_VM(8);     // own K(t) writes landed (V(t) up to 8 still in flight)
    bar();          // all waves: K(t) resident

    // ---- swapped QK^T: S^T(32x32) = K(32x256) x Q(32x256)^T ----
    f32x4 s[2][2];
#pragma unroll
    for (int qh = 0; qh < 2; ++qh)
#pragma unroll
      for (int j = 0; j < 2; ++j) s[qh][j] = zero4();
    __builtin_amdgcn_s_setprio(1);
#pragma unroll
    for (int kc = 0; kc < 8; ++kc) {
      bf16x8 kf[2];
#pragma unroll
      for (int j = 0; j < 2; ++j)
        kf[j] = *(const bf16x8*)(KB + (j * 16 + r15) * 512 +
                                 (((kc * 4 + lg) ^ rs7) << 4));
#pragma unroll
      for (int qh = 0; qh < 2; ++qh)
#pragma unroll
        for (int j = 0; j < 2; ++j) s[qh][j] = mfma16(kf[j], qf[qh][kc], s[qh][j]);
    }
    __builtin_amdgcn_s_setprio(0);
    // lane holds S[kv=j*16+lg*4+r][q=qh*16+r15]
    // ---- online softmax per q-half ----
    bf16x4 pk[2][2];
#pragma unroll
    for (int qh = 0; qh < 2; ++qh) {
      float pmax = s[qh][0][0];
#pragma unroll
      for (int j = 0; j < 2; ++j)
#pragma unroll
        for (int r = 0; r < 4; ++r) pmax = fmaxf(pmax, s[qh][j][r]);
      pmax = fmaxf(pmax, __shfl_xor(pmax, 16, 64));
      pmax = fmaxf(pmax, __shfl_xor(pmax, 32, 64));
      if (!__all(pmax <= mrun[qh] + 8.f)) {  // defer-rescale
        const float mn = fmaxf(mrun[qh], pmax);
        const float scl = exp2f(mrun[qh] - mn);
        mrun[qh] = mn;
        lrun[qh] *= scl;
#pragma unroll
        for (int d = 0; d < 16; ++d) po[d][qh] *= scl;
      }
      float psum = 0.f;
#pragma unroll
      for (int j = 0; j < 2; ++j)
#pragma unroll
        for (int r = 0; r < 4; ++r) {
          const float pv = exp2f(s[qh][j][r] - mrun[qh]);
          psum += pv;
          pk[qh][j][r] = (__bf16)pv;
        }
      psum += __shfl_xor(psum, 16, 64);
      psum += __shfl_xor(psum, 32, 64);
      lrun[qh] += psum;
    }
    // ---- P -> per-wave LDS: [32 q][32 kv], 16B-slot XOR swz ----
#pragma unroll
    for (int qh = 0; qh < 2; ++qh)
#pragma unroll
      for (int j = 0; j < 2; ++j) {
        const int prow = qh * 16 + r15;
        const int slot = (j * 2 + (lg >> 1)) ^ pswz;
        *(bf16x4*)(P + prow * 64 + (slot << 4) + ((lg & 1) * 8)) = pk[qh][j];
      }

    WAIT_VM(0);     // own V(t) writes landed (K(t+1) not yet issued)
    bar();          // all waves: V(t) resident; done reading KB
    if (t < 15) stageK(n0n);   // overwrite KB, hides under PV

    // ---- swapped PV: O^T(256x32) += V^T(256x32) x P(32x32)^T ----
    bf16x8 pb[2];
#pragma unroll
    for (int qh = 0; qh < 2; ++qh) {
      const int prow = qh * 16 + r15;
      pb[qh] = *(const bf16x8*)(P + prow * 64 + ((lg ^ pswz) << 4));
    }
    __builtin_amdgcn_s_setprio(1);
#pragma unroll
    for (int df = 0; df < 16; ++df) {
      const int vrow = df * 16 + r15;
      const bf16x8 vf = *(const bf16x8*)(VB + vrow * 64 +
                                         ((lg ^ ((vrow ^ (vrow >> 2)) & 3)) << 4));
#pragma unroll
      for (int qh = 0; qh < 2; ++qh) po[df][qh] = mfma16(vf, pb[qh], po[df][qh]);
    }
    __builtin_amdgcn_s_setprio(0);
    bar();          // all waves done reading VB
    if (t < 15) stageV(n0n);   // hides under next QK^T
  }

  // ---- in-block flash-merge of the two kv-halves (wave w2 <-> wave 2+w2) ----
  __syncthreads();   // full barrier incl. lgkm drain before LDS reuse
  if (grp == 1) {
    f32x4 ml = {mrun[0], mrun[1], lrun[0], lrun[1]};
    *(f32x4*)(smem + 65536 + ((w2 * 64 + lane) << 4)) = ml;
#pragma unroll
    for (int qh = 0; qh < 2; ++qh)
#pragma unroll
      for (int df = 0; df < 16; ++df) {
        bf16x4 t;
#pragma unroll
        for (int r = 0; r < 4; ++r) t[r] = (__bf16)(po[df][qh][r]);
        *(bf16x4*)(smem + w2 * 16384 + (qh * 16 + df) * 512 + lane * 8) = t;
      }
  }
  __syncthreads();
  if (grp == 0) {
    const f32x4 ml = *(const f32x4*)(smem + 65536 + ((w2 * 64 + lane) << 4));
#pragma unroll
    for (int qh = 0; qh < 2; ++qh) {
      const float m1 = ml[qh], l1 = ml[2 + qh];
      const float M = fmaxf(mrun[qh], m1);
      const float a0 = exp2f(mrun[qh] - M), a1 = exp2f(m1 - M);
      const float inv = 1.f / (a0 * lrun[qh] + a1 * l1);
      __bf16* ob = o + (((size_t)(b * 1024 + m0 + qh * 16 + r15)) << 8);
#pragma unroll
      for (int df = 0; df < 16; ++df) {
        const bf16x4 p1 =
            *(const bf16x4*)(smem + w2 * 16384 + (qh * 16 + df) * 512 + lane * 8);
        bf16x4 t;
#pragma unroll
        for (int r = 0; r < 4; ++r)
          t[r] = (__bf16)((a0 * po[df][qh][r] + a1 * (float)p1[r]) * inv);
        *(bf16x4*)(ob + df * 16 + lg * 4) = t;
      }
    }
  }
}

// ---------------------------------------------------------------------------
// Kernel 5: proj GEMM + bias + residual, writes fp32 out in (B,C,S,S).
// ---------------------------------------------------------------------------
__global__ __launch_bounds__(256) void proj_gemm(
    const __bf16* __restrict__ o, const __bf16* __restrict__ wpb,
    const float* __restrict__ b_proj, const float* __restrict__ x,
    float* __restrict__ out) {
  __shared__ __align__(16) __bf16 lA[128 * 64], lB[128 * 64];
  const int nt = blockIdx.x, mt = blockIdx.y;
  const int tid = threadIdx.x, lane = tid & 63, wave = tid >> 6;
  f32x4 acc[4][4];
  gemm_core_k256(o + (size_t)mt * 128 * 256, wpb + (size_t)nt * 128 * 256,
                 lA, lB, lane, wave, acc);

  const int wm = (wave >> 1) * 64, wn = (wave & 1) * 64;
  const int r15 = lane & 15, lg = lane >> 4;
#pragma unroll
  for (int j = 0; j < 4; ++j) {
    const int c = nt * 128 + wn + j * 16 + r15;
    const float bias = b_proj[c];
#pragma unroll
    for (int i = 0; i < 4; ++i) {
      const int mbase = mt * 128 + wm + i * 16 + lg * 4;
      const int b = mbase >> 10, p = mbase & 1023;
      const size_t off = (((size_t)(b * 256 + c)) << 10) + p;
      f32x4 xv = *(const f32x4*)(x + off);
      f32x4 r = acc[i][j];
      r = r + xv;
      r = r + bias;
      *(f32x4*)(out + off) = r;
    }
  }
}

// ---------------------------------------------------------------------------
// Launcher
// ---------------------------------------------------------------------------
extern "C" void kernel_launch(void* const* d_in, const int* in_sizes, int n_in,
                              void* d_out, int out_size, void* d_ws, size_t ws_size,
                              hipStream_t stream) {
  const float* x      = (const float*)d_in[0];
  // d_in[1] = t_embd (unused by reference)
  const float* gamma  = (const float*)d_in[2];
  const float* beta   = (const float*)d_in[3];
  const float* w_attn = (const float*)d_in[4];
  const float* b_attn = (const float*)d_in[5];
  const float* w_proj = (const float*)d_in[6];
  const float* b_proj = (const float*)d_in[7];
  float* out = (float*)d_out;

  char* ws = (char*)d_ws;
  __bf16* h   = (__bf16*)(ws);                          // 16MB, reused as o
  __bf16* qb  = (__bf16*)(ws + ((size_t)16 << 20));     // 16MB
  __bf16* kb  = (__bf16*)(ws + ((size_t)32 << 20));     // 16MB
  __bf16* vtb = (__bf16*)(ws + ((size_t)48 << 20));     // 16MB, [B][C][P]
  __bf16* wab = (__bf16*)(ws + ((size_t)64 << 20));     // 384KB
  __bf16* wpb = wab + 196608;                           // 128KB

  cvt_weights<<<1024, 256, 0, stream>>>(w_attn, w_proj, wab, wpb);
  gn_fused<<<1024, 256, 0, stream>>>(x, gamma, beta, h);
  qkv_gemm<<<dim3(6, 256), 256, 0, stream>>>(h, wab, b_attn, qb, kb, vtb);
  attn<<<512, 256, 73728, stream>>>(qb, kb, vtb, h /* o reuses h */);
  proj_gemm<<<dim3(2, 256), 256, 0, stream>>>(h, wpb, b_proj, x, out);
}

// Round 11
// 134.359 us; speedup vs baseline: 1.1667x; 1.1667x over previous
//
#include <hip/hip_runtime.h>
#include <hip/hip_bf16.h>
#include <stdint.h>
#include <stddef.h>

// ---------------------------------------------------------------------------
// ResAttnBlock: GroupNorm -> QKV -> full spatial attention -> proj -> residual
// B=32, C=256, S=32 (P=1024 positions), 32 groups of 8 channels.
// All GEMM-shaped work on v_mfma_f32_16x16x32_bf16; fp32 accumulate.
// ---------------------------------------------------------------------------

typedef float  f32x4  __attribute__((ext_vector_type(4)));
typedef __bf16 bf16x8 __attribute__((ext_vector_type(8)));
typedef __bf16 bf16x4 __attribute__((ext_vector_type(4)));

#define DEVI static __device__ __forceinline__

DEVI f32x4 mfma16(bf16x8 a, bf16x8 b, f32x4 c) {
  return __builtin_amdgcn_mfma_f32_16x16x32_bf16(a, b, c, 0, 0, 0);
}

DEVI f32x4 zero4() { f32x4 z = {0.f, 0.f, 0.f, 0.f}; return z; }

typedef const __attribute__((address_space(1))) void* gas_cvp;
typedef __attribute__((address_space(3))) void*       las_vp;

DEVI void gl_lds16(const __bf16* g, __bf16* l) {
  // async global->LDS, 16B per lane; LDS dest = uniform base + lane*16
  __builtin_amdgcn_global_load_lds((gas_cvp)g, (las_vp)l, 16, 0, 0);
}

#define WAIT_VM(N) asm volatile("s_waitcnt vmcnt(" #N ")" ::: "memory")
DEVI void bar() {
  asm volatile("" ::: "memory");
  __builtin_amdgcn_s_barrier();
  asm volatile("" ::: "memory");
}

// ---------------------------------------------------------------------------
// Kernel 0: convert weights to bf16 (w_attn 768x256, w_proj 256x256)
// ---------------------------------------------------------------------------
__global__ __launch_bounds__(256) void cvt_weights(
    const float* __restrict__ wa, const float* __restrict__ wp,
    __bf16* __restrict__ wab, __bf16* __restrict__ wpb) {
  const int i = blockIdx.x * 256 + threadIdx.x;
  if (i < 196608) {
    wab[i] = (__bf16)wa[i];
  } else {
    const int j = i - 196608;
    if (j < 65536) wpb[j] = (__bf16)wp[j];
  }
}

// ---------------------------------------------------------------------------
// Kernel 1: fused GroupNorm (stats + apply + transpose), single x pass.
// ---------------------------------------------------------------------------
__global__ __launch_bounds__(256) void gn_fused(
    const float* __restrict__ x, const float* __restrict__ gamma,
    const float* __restrict__ beta, __bf16* __restrict__ h) {
  __shared__ __align__(16) float xs[8192];
  __shared__ float redS[4], redSS[4];
  const int bg = blockIdx.x;           // b*32+g
  const int b = bg >> 5, g = bg & 31;
  const int tid = threadIdx.x;
  const float* base = x + (size_t)bg * 8192;
  float s = 0.f, ss = 0.f;
#pragma unroll
  for (int it = 0; it < 8; ++it) {
    const int i = it * 256 + tid;      // f32x4 chunk index
    f32x4 v = *(const f32x4*)(base + i * 4);
    *(f32x4*)(xs + i * 4) = v;
    s  += v[0] + v[1] + v[2] + v[3];
    ss += v[0]*v[0] + v[1]*v[1] + v[2]*v[2] + v[3]*v[3];
  }
#pragma unroll
  for (int m = 1; m < 64; m <<= 1) {
    s  += __shfl_xor(s,  m, 64);
    ss += __shfl_xor(ss, m, 64);
  }
  const int lane = tid & 63, wave = tid >> 6;
  if (lane == 0) { redS[wave] = s; redSS[wave] = ss; }
  __syncthreads();
  const float S  = redS[0] + redS[1] + redS[2] + redS[3];
  const float SS = redSS[0] + redSS[1] + redSS[2] + redSS[3];
  const float mu = S * (1.f / 8192.f);
  const float rstd = rsqrtf(SS * (1.f / 8192.f) - mu * mu + 1e-5f);
  float ga[8], be[8];
#pragma unroll
  for (int j = 0; j < 8; ++j) {
    const int c = g * 8 + j;
    ga[j] = gamma[c] * rstd;
    be[j] = beta[c] - mu * ga[j];
  }
  __bf16* hb = h + ((size_t)b << 18) + g * 8;   // h[b][p][c]
#pragma unroll
  for (int it = 0; it < 4; ++it) {
    const int p = it * 256 + tid;
    bf16x8 o8;
#pragma unroll
    for (int j = 0; j < 8; ++j)
      o8[j] = (__bf16)(xs[j * 1024 + p] * ga[j] + be[j]);
    *(bf16x8*)(hb + ((size_t)p << 8)) = o8;
  }
}

// ---------------------------------------------------------------------------
// Shared GEMM core: C(128x128) = A(128xK=256) * Bt(128 rows x 256)^T
// 4 waves (2x2), each 64x64 = 4x4 frags. BK=64, 4 k-outer steps.
// ---------------------------------------------------------------------------
DEVI void gemm_core_k256(const __bf16* __restrict__ A0, const __bf16* __restrict__ B0,
                         __bf16* lA, __bf16* lB, int lane, int wave, f32x4 acc[4][4]) {
  const int wm = (wave >> 1) * 64;
  const int wn = (wave & 1) * 64;
  const int r15 = lane & 15, lg = lane >> 4;
#pragma unroll
  for (int i = 0; i < 4; ++i)
#pragma unroll
    for (int j = 0; j < 4; ++j) acc[i][j] = zero4();

  for (int ko = 0; ko < 4; ++ko) {
#pragma unroll
    for (int it = 0; it < 4; ++it) {
      const int q = wave * 256 + it * 64 + lane;
      const int row = q >> 3, c8 = q & 7;
      const int srcoff = row * 256 + ko * 64 + ((c8 ^ (row & 7)) << 3);
      gl_lds16(A0 + srcoff, lA + (size_t)(wave * 256 + it * 64) * 8);
      gl_lds16(B0 + srcoff, lB + (size_t)(wave * 256 + it * 64) * 8);
    }
    __syncthreads();
#pragma unroll
    for (int kk = 0; kk < 2; ++kk) {
      bf16x8 af[4], bfr[4];
#pragma unroll
      for (int i = 0; i < 4; ++i) {
        const int row = wm + i * 16 + r15;
        af[i] = *(const bf16x8*)((const char*)lA + row * 128 +
                                 (((kk * 4 + lg) ^ (row & 7)) << 4));
      }
#pragma unroll
      for (int j = 0; j < 4; ++j) {
        const int row = wn + j * 16 + r15;
        bfr[j] = *(const bf16x8*)((const char*)lB + row * 128 +
                                  (((kk * 4 + lg) ^ (row & 7)) << 4));
      }
#pragma unroll
      for (int i = 0; i < 4; ++i)
#pragma unroll
        for (int j = 0; j < 4; ++j) acc[i][j] = mfma16(af[i], bfr[j], acc[i][j]);
    }
    __syncthreads();
  }
}

// ---------------------------------------------------------------------------
// Kernel 3: QKV GEMM. h(32768x256) @ w_attn(768x256)^T + bias.
// ---------------------------------------------------------------------------
__global__ __launch_bounds__(256) void qkv_gemm(
    const __bf16* __restrict__ h, const __bf16* __restrict__ wab,
    const float* __restrict__ b_attn,
    __bf16* __restrict__ q, __bf16* __restrict__ k, __bf16* __restrict__ vt) {
  __shared__ __align__(16) __bf16 lA[128 * 64], lB[128 * 64];
  const int nt = blockIdx.x, mt = blockIdx.y;
  const int tid = threadIdx.x, lane = tid & 63, wave = tid >> 6;
  f32x4 acc[4][4];
  gemm_core_k256(h + (size_t)mt * 128 * 256, wab + (size_t)nt * 128 * 256,
                 lA, lB, lane, wave, acc);

  const int wm = (wave >> 1) * 64, wn = (wave & 1) * 64;
  const int r15 = lane & 15, lg = lane >> 4;
  const int sec = nt >> 1;  // 0=q, 1=k, 2=v
  const float QS = 0.0625f * 1.44269504088896340736f;  // (1/sqrt(256))*log2(e)
#pragma unroll
  for (int j = 0; j < 4; ++j) {
    const int ng = nt * 128 + wn + j * 16 + r15;
    const float bias = b_attn[ng];
    const int c = ng & 255;
#pragma unroll
    for (int i = 0; i < 4; ++i) {
      const int mbase = mt * 128 + wm + i * 16 + lg * 4;
      if (sec == 0) {
#pragma unroll
        for (int r = 0; r < 4; ++r)
          q[(size_t)(mbase + r) * 256 + c] = (__bf16)((acc[i][j][r] + bias) * QS);
      } else if (sec == 1) {
#pragma unroll
        for (int r = 0; r < 4; ++r)
          k[(size_t)(mbase + r) * 256 + c] = (__bf16)(acc[i][j][r] + bias);
      } else {
        const int b = mbase >> 10, p = mbase & 1023;
        bf16x4 pk;
#pragma unroll
        for (int r = 0; r < 4; ++r) pk[r] = (__bf16)(acc[i][j][r] + bias);
        *(bf16x4*)(vt + (((size_t)(b * 256 + c)) << 10) + p) = pk;
      }
    }
  }
}

// ---------------------------------------------------------------------------
// Kernel 4: flash attention. R7's proven m=16 structure (best: 61.6us) with
// KVBLK 64->32: LDS 36KB -> 4 blocks/CU (4 waves/SIMD, double R7's TLP).
// Per-iter serial chain halves; 4 independent barrier-domains per CU hide
// the vmcnt/barrier/softmax stalls that pinned R7 at 50% issue. m=32
// variants (R6/R8/R9/R10) all refuted: VGPR footprint kills occupancy.
// LDS: lK @0 [32][256] 16KB, lV @16384 [256][32] 16KB, P @32768+wave*1024.
// ---------------------------------------------------------------------------
__global__ __launch_bounds__(256, 1) void attn(
    const __bf16* __restrict__ q, const __bf16* __restrict__ k,
    const __bf16* __restrict__ vt, __bf16* __restrict__ o) {
  extern __shared__ __align__(16) char smem[];   // 36864 B

  const int bid = blockIdx.x;
  const int xcd = bid & 7, sub = bid >> 3;       // sub 0..63
  const int b = xcd * 4 + (sub & 3);             // same-b blocks share an XCD
  const int qt = sub >> 2;                       // 0..15
  const int tid = threadIdx.x, lane = tid & 63, wave = tid >> 6;
  const int r15 = lane & 15, lg = lane >> 4, rs7 = r15 & 7;
  const int m0 = qt * 64 + wave * 16;
  char* lK = smem;
  char* lV = smem + 16384;
  char* P  = smem + 32768 + wave * 1024;         // [16 q][32 kv] bf16, 64B rows

  const __bf16* kb = k  + ((size_t)b << 18);
  const __bf16* vb = vt + ((size_t)b << 18);
  const int pswz = (r15 ^ (r15 >> 2)) & 3;       // 64B-row swizzle

  // Q fragments in registers: 8 k-chunks (32 VGPR); B-operand layout
  const __bf16* qbp = q + (((size_t)(b * 1024 + m0)) << 8);
  bf16x8 qf[8];
#pragma unroll
  for (int kc = 0; kc < 8; ++kc)
    qf[kc] = *(const bf16x8*)(qbp + ((size_t)r15) * 256 + kc * 32 + lg * 8);

  f32x4 po[16];   // O^T: po[df][r] = O[q=r15][d=df*16+lg*4+r]
#pragma unroll
  for (int d = 0; d < 16; ++d) po[d] = zero4();
  float mrun = -1e30f, lrun = 0.f;   // per-lane (q-row r15, replicated x4 lg)

  // staging: 1024 16B-chunks per tile, 4 per thread, pre-swizzled source
  auto stageK = [&](int n0) {
    __bf16* dst = (__bf16*)lK;
#pragma unroll
    for (int it = 0; it < 4; ++it) {
      const int qch = it * 256 + tid;            // [32 rows][32 chunks]
      const int row = qch >> 5, c32 = qch & 31;
      gl_lds16(kb + (size_t)(n0 + row) * 256 + ((c32 ^ (row & 7)) << 3),
               dst + (size_t)(it * 256 + wave * 64) * 8);
    }
  };
  auto stageV = [&](int n0) {
    __bf16* dst = (__bf16*)lV;
#pragma unroll
    for (int it = 0; it < 4; ++it) {
      const int qch = it * 256 + tid;            // [256 rows][4 chunks]
      const int row = qch >> 2, c4 = qch & 3;
      gl_lds16(vb + ((size_t)row << 10) + n0 + ((c4 ^ ((row ^ (row >> 2)) & 3)) << 3),
               dst + (size_t)(it * 256 + wave * 64) * 8);
    }
  };

  stageK(0);
  stageV(0);

  for (int t = 0; t < 32; ++t) {
    const int n0n = (t + 1) * 32;
    WAIT_VM(4);     // own K(t) writes landed (V(t)'s 4 still in flight)
    bar();          // all waves: K(t) resident

    // ---- swapped QK^T: S^T(32x16) = K(32x256) x Q(16x256)^T ----
    f32x4 s[2];
    s[0] = zero4(); s[1] = zero4();
    __builtin_amdgcn_s_setprio(1);
#pragma unroll
    for (int kc = 0; kc < 8; ++kc) {
      bf16x8 kf[2];
#pragma unroll
      for (int j = 0; j < 2; ++j)
        kf[j] = *(const bf16x8*)(lK + (j * 16 + r15) * 512 +
                                 (((kc * 4 + lg) ^ rs7) << 4));
#pragma unroll
      for (int j = 0; j < 2; ++j) s[j] = mfma16(kf[j], qf[kc], s[j]);
    }
    __builtin_amdgcn_s_setprio(0);
    // lane holds S[kv=j*16+lg*4+r][qrow=r15]
    // ---- online softmax: in-reg max/sum + 2 shfl steps ----
    float pmax = s[0][0];
#pragma unroll
    for (int j = 0; j < 2; ++j)
#pragma unroll
      for (int r = 0; r < 4; ++r) pmax = fmaxf(pmax, s[j][r]);
    pmax = fmaxf(pmax, __shfl_xor(pmax, 16, 64));
    pmax = fmaxf(pmax, __shfl_xor(pmax, 32, 64));
    if (!__all(pmax <= mrun + 8.f)) {   // defer-rescale: P bounded by 2^8
      const float mn = fmaxf(mrun, pmax);
      const float scl = exp2f(mrun - mn);
      mrun = mn;
      lrun *= scl;
#pragma unroll
      for (int d = 0; d < 16; ++d) po[d] *= scl;
    }
    float psum = 0.f;
    bf16x4 pk[2];
#pragma unroll
    for (int j = 0; j < 2; ++j)
#pragma unroll
      for (int r = 0; r < 4; ++r) {
        const float pv = exp2f(s[j][r] - mrun);
        psum += pv;
        pk[j][r] = (__bf16)pv;
      }
    psum += __shfl_xor(psum, 16, 64);
    psum += __shfl_xor(psum, 32, 64);
    lrun += psum;
    // ---- P -> per-wave LDS: [16 q][32 kv], 16B-slot XOR swz ----
#pragma unroll
    for (int j = 0; j < 2; ++j) {
      const int slot = (j * 2 + (lg >> 1)) ^ pswz;
      *(bf16x4*)(P + r15 * 64 + (slot << 4) + ((lg & 1) * 8)) = pk[j];
    }

    WAIT_VM(0);     // own V(t) writes landed (K(t+1) not yet issued)
    bar();          // all waves: V(t) resident; done reading lK
    if (t < 31) stageK(n0n);   // overwrite lK, hides under PV

    // ---- swapped PV: O^T(256x16) += V^T(256x32) x P(16x32)^T ----
    const bf16x8 pb = *(const bf16x8*)(P + r15 * 64 + ((lg ^ pswz) << 4));
    __builtin_amdgcn_s_setprio(1);
#pragma unroll
    for (int df = 0; df < 16; ++df) {
      const int vrow = df * 16 + r15;
      const bf16x8 vf = *(const bf16x8*)(lV + vrow * 64 +
                                         ((lg ^ ((vrow ^ (vrow >> 2)) & 3)) << 4));
      po[df] = mfma16(vf, pb, po[df]);
    }
    __builtin_amdgcn_s_setprio(0);
    bar();          // all waves done reading lV
    if (t < 31) stageV(n0n);   // hides under next QK^T
  }
  // ---- epilogue: O/l, 4 consecutive d per reg quad -> bf16x4 stores ----
  const float inv = 1.f / lrun;
  __bf16* ob = o + (((size_t)(b * 1024 + m0 + r15)) << 8);
#pragma unroll
  for (int df = 0; df < 16; ++df) {
    bf16x4 t;
#pragma unroll
    for (int r = 0; r < 4; ++r) t[r] = (__bf16)(po[df][r] * inv);
    *(bf16x4*)(ob + df * 16 + lg * 4) = t;
  }
}

// ---------------------------------------------------------------------------
// Kernel 5: proj GEMM + bias + residual, writes fp32 out in (B,C,S,S).
// ---------------------------------------------------------------------------
__global__ __launch_bounds__(256) void proj_gemm(
    const __bf16* __restrict__ o, const __bf16* __restrict__ wpb,
    const float* __restrict__ b_proj, const float* __restrict__ x,
    float* __restrict__ out) {
  __shared__ __align__(16) __bf16 lA[128 * 64], lB[128 * 64];
  const int nt = blockIdx.x, mt = blockIdx.y;
  const int tid = threadIdx.x, lane = tid & 63, wave = tid >> 6;
  f32x4 acc[4][4];
  gemm_core_k256(o + (size_t)mt * 128 * 256, wpb + (size_t)nt * 128 * 256,
                 lA, lB, lane, wave, acc);

  const int wm = (wave >> 1) * 64, wn = (wave & 1) * 64;
  const int r15 = lane & 15, lg = lane >> 4;
#pragma unroll
  for (int j = 0; j < 4; ++j) {
    const int c = nt * 128 + wn + j * 16 + r15;
    const float bias = b_proj[c];
#pragma unroll
    for (int i = 0; i < 4; ++i) {
      const int mbase = mt * 128 + wm + i * 16 + lg * 4;
      const int b = mbase >> 10, p = mbase & 1023;
      const size_t off = (((size_t)(b * 256 + c)) << 10) + p;
      f32x4 xv = *(const f32x4*)(x + off);
      f32x4 r = acc[i][j];
      r = r + xv;
      r = r + bias;
      *(f32x4*)(out + off) = r;
    }
  }
}

// ---------------------------------------------------------------------------
// Launcher
// ---------------------------------------------------------------------------
extern "C" void kernel_launch(void* const* d_in, const int* in_sizes, int n_in,
                              void* d_out, int out_size, void* d_ws, size_t ws_size,
                              hipStream_t stream) {
  const float* x      = (const float*)d_in[0];
  // d_in[1] = t_embd (unused by reference)
  const float* gamma  = (const float*)d_in[2];
  const float* beta   = (const float*)d_in[3];
  const float* w_attn = (const float*)d_in[4];
  const float* b_attn = (const float*)d_in[5];
  const float* w_proj = (const float*)d_in[6];
  const float* b_proj = (const float*)d_in[7];
  float* out = (float*)d_out;

  char* ws = (char*)d_ws;
  __bf16* h   = (__bf16*)(ws);                          // 16MB, reused as o
  __bf16* qb  = (__bf16*)(ws + ((size_t)16 << 20));     // 16MB
  __bf16* kb  = (__bf16*)(ws + ((size_t)32 << 20));     // 16MB
  __bf16* vtb = (__bf16*)(ws + ((size_t)48 << 20));     // 16MB, [B][C][P]
  __bf16* wab = (__bf16*)(ws + ((size_t)64 << 20));     // 384KB
  __bf16* wpb = wab + 196608;                           // 128KB

  cvt_weights<<<1024, 256, 0, stream>>>(w_attn, w_proj, wab, wpb);
  gn_fused<<<1024, 256, 0, stream>>>(x, gamma, beta, h);
  qkv_gemm<<<dim3(6, 256), 256, 0, stream>>>(h, wab, b_attn, qb, kb, vtb);
  attn<<<512, 256, 36864, stream>>>(qb, kb, vtb, h /* o reuses h */);
  proj_gemm<<<dim3(2, 256), 256, 0, stream>>>(h, wpb, b_proj, x, out);
}